// Round 1
// baseline (50.289 us; speedup 1.0000x reference)
//
#include <hip/hip_runtime.h>

// Problem constants
#define NB   64    // B
#define DD   256   // D
#define TT   512   // T
#define KK   512   // K

typedef short bf8 __attribute__((ext_vector_type(8)));   // 8 x bf16 bits (16B, 4 VGPR)
typedef float f4  __attribute__((ext_vector_type(4)));   // MFMA acc

__device__ inline unsigned short f2bf(float x) {
  unsigned u = __float_as_uint(x);
  u += 0x7FFFu + ((u >> 16) & 1u);   // round-to-nearest-even
  return (unsigned short)(u >> 16);
}

// D = A*B + D   (A rows = codewords k, B cols = t, reduction = d)
#define MFMA(accv, va, vb) \
  asm("v_mfma_f32_16x16x32_bf16 %0, %1, %2, %0" : "+v"(accv) : "v"(va), "v"(vb))

#define ACCLIST(acc) \
    "+v"(acc[0][0]), "+v"(acc[0][1]), "+v"(acc[0][2]), "+v"(acc[0][3]), \
    "+v"(acc[1][0]), "+v"(acc[1][1]), "+v"(acc[1][2]), "+v"(acc[1][3]), \
    "+v"(acc[2][0]), "+v"(acc[2][1]), "+v"(acc[2][2]), "+v"(acc[2][3]), \
    "+v"(acc[3][0]), "+v"(acc[3][1]), "+v"(acc[3][2]), "+v"(acc[3][3])

// ---------------------------------------------------------------------------
// Kernel 1: transpose M [D][K] fp32 -> Mt_bf [K][D] bf16, compute mnorm[k],
//           and zero the 3 accumulators (block 0).
// ---------------------------------------------------------------------------
__global__ __launch_bounds__(256) void edm_prep_m(
    const float* __restrict__ M, unsigned short* __restrict__ Mt,
    float* __restrict__ mnorm, float* __restrict__ accums) {
  const int k = blockIdx.x;      // 0..511
  const int d = threadIdx.x;     // 0..255
  const float v = M[(size_t)d * KK + k];
  Mt[(size_t)k * DD + d] = f2bf(v);
  float s = v * v;
  #pragma unroll
  for (int off = 32; off > 0; off >>= 1) s += __shfl_down(s, off);
  __shared__ float ps[4];
  if ((threadIdx.x & 63) == 0) ps[threadIdx.x >> 6] = s;
  __syncthreads();
  if (threadIdx.x == 0) {
    mnorm[k] = ps[0] + ps[1] + ps[2] + ps[3];
    if (k == 0) { accums[0] = 0.f; accums[1] = 0.f; accums[2] = 0.f; }
  }
}

// ---------------------------------------------------------------------------
// Kernel 2: sum (Xhat-X)^2 (262144 elems) and sum Dhat (32768 elems).
// ---------------------------------------------------------------------------
__global__ __launch_bounds__(256) void edm_rec(
    const float4* __restrict__ Xh, const float4* __restrict__ X,
    const float4* __restrict__ Dh, float* __restrict__ accums) {
  const int gid = blockIdx.x * 256 + threadIdx.x;   // 65536 threads, one float4 each
  const float4 a = Xh[gid];
  const float4 c = X[gid];
  const float e0 = a.x - c.x, e1 = a.y - c.y, e2 = a.z - c.z, e3 = a.w - c.w;
  float s = e0 * e0 + e1 * e1 + e2 * e2 + e3 * e3;
  float sd = 0.f;
  if (gid < 8192) { const float4 dd = Dh[gid]; sd = dd.x + dd.y + dd.z + dd.w; }
  #pragma unroll
  for (int off = 32; off > 0; off >>= 1) {
    s  += __shfl_down(s, off);
    sd += __shfl_down(sd, off);
  }
  __shared__ float ps[8];
  const int w = threadIdx.x >> 6;
  if ((threadIdx.x & 63) == 0) { ps[w] = s; ps[4 + w] = sd; }
  __syncthreads();
  if (threadIdx.x == 0) {
    atomicAdd(&accums[0], ps[0] + ps[1] + ps[2] + ps[3]);
    atomicAdd(&accums[1], ps[4] + ps[5] + ps[6] + ps[7]);
  }
}

// ---------------------------------------------------------------------------
// Kernel 3: main. One block per (b, t-tile of 64). Computes
//   d2min[t] = min_k (||m_k||^2 - 2 h_t . m_k) + ||h_t||^2
// via bf16 MFMA, then atomicAdd(sum_t d2min) into accums[2].
// ---------------------------------------------------------------------------
__global__ __launch_bounds__(256) void edm_main(
    const float* __restrict__ H, const unsigned short* __restrict__ Mt,
    const float* __restrict__ mnorm, float* __restrict__ accums) {
  __shared__ __align__(16) float scratch[64][68];           // fp32 transpose staging (padded)
  __shared__ __align__(16) unsigned short Hbf[64 * 256];    // [t][d] bf16, XOR-swizzled rows
  __shared__ float hsum[64];
  __shared__ float wmin[4][64];

  const int tid = threadIdx.x;
  const int b   = blockIdx.x >> 3;
  const int t0  = (blockIdx.x & 7) << 6;
  const float* Hb = H + (size_t)b * DD * TT + t0;

  if (tid < 64) hsum[tid] = 0.f;

  const int tcol = tid & 63;   // owned t (pass B)
  const int q    = tid >> 6;   // d sub-range within chunk
  float hacc = 0.f;

  for (int ch = 0; ch < 4; ++ch) {              // 4 chunks of 64 d-rows
    // pass A: coalesced global -> fp32 scratch [dl][t]
    #pragma unroll
    for (int ii = 0; ii < 4; ++ii) {
      const int f  = ii * 256 + tid;
      const int dl = f >> 4;
      const int t4 = f & 15;
      const float4 v = *(const float4*)(Hb + (size_t)(ch * 64 + dl) * TT + (t4 << 2));
      *(float4*)&scratch[dl][t4 << 2] = v;
    }
    __syncthreads();
    // pass B: column read (conflict-free), convert, pack, swizzled b128 write
    unsigned int wpk[8];
    #pragma unroll
    for (int jj = 0; jj < 8; ++jj) {
      const float x0 = scratch[q * 16 + 2 * jj + 0][tcol];
      const float x1 = scratch[q * 16 + 2 * jj + 1][tcol];
      hacc += x0 * x0 + x1 * x1;
      wpk[jj] = (unsigned)f2bf(x0) | ((unsigned)f2bf(x1) << 16);
    }
    const int dbase2 = (ch * 64 + q * 16) * 2;    // unswizzled byte offset within row
    char* rowp = (char*)Hbf + tcol * 512;
    const int swz = (tcol & 7) << 4;
    *(uint4*)(rowp + ((dbase2 +  0) ^ swz)) = make_uint4(wpk[0], wpk[1], wpk[2], wpk[3]);
    *(uint4*)(rowp + ((dbase2 + 16) ^ swz)) = make_uint4(wpk[4], wpk[5], wpk[6], wpk[7]);
    __syncthreads();   // protects scratch reuse AND (final iter) Hbf completion
  }
  atomicAdd(&hsum[tcol], hacc);   // consumed only after the post-wmin barrier

  // ---- MFMA phase: wave wv owns codewords [p*256 + wv*64, +64) per pass p ----
  const int l   = tid & 63;
  const int wv  = tid >> 6;
  const int r16 = l & 15;
  const int g   = l >> 4;

  float rmin[4] = {3.0e38f, 3.0e38f, 3.0e38f, 3.0e38f};   // per t-subtile tn

  #pragma unroll
  for (int p = 0; p < 2; ++p) {
    const int kb = p * 256 + wv * 64;
    f4 acc[4][4];
    #pragma unroll
    for (int kt = 0; kt < 4; ++kt)
      #pragma unroll
      for (int tn = 0; tn < 4; ++tn)
        acc[kt][tn] = (f4){0.f, 0.f, 0.f, 0.f};
    asm volatile("s_nop 1" : ACCLIST(acc));   // VALU-write -> MFMA-read-C hazard guard

    #pragma unroll
    for (int ds = 0; ds < 8; ++ds) {          // 8 x K=32 over d
      bf8 afr[4];
      #pragma unroll
      for (int kt = 0; kt < 4; ++kt)
        afr[kt] = *(const bf8*)(Mt + (size_t)(kb + kt * 16 + r16) * DD + ds * 32 + g * 8);
      #pragma unroll
      for (int tn = 0; tn < 4; ++tn) {
        const int t = tn * 16 + r16;
        const bf8 bfr = *(const bf8*)((const char*)Hbf + t * 512 +
                                      ((ds * 64 + g * 16) ^ ((t & 7) << 4)));
        MFMA(acc[0][tn], afr[0], bfr);
        MFMA(acc[1][tn], afr[1], bfr);
        MFMA(acc[2][tn], afr[2], bfr);
        MFMA(acc[3][tn], afr[3], bfr);
      }
    }
    asm volatile("s_nop 7\n\ts_nop 7" : ACCLIST(acc));  // MFMA-write -> VALU-read hazard guard

    // fold: d2_partial = mnorm[k] - 2*dot ; k = kb + kt*16 + 4*g + rr (C/D row map)
    #pragma unroll
    for (int kt = 0; kt < 4; ++kt) {
      const f4 mn = *(const f4*)(mnorm + kb + kt * 16 + g * 4);
      #pragma unroll
      for (int tn = 0; tn < 4; ++tn) {
        #pragma unroll
        for (int rr = 0; rr < 4; ++rr) {
          const float d2 = mn[rr] - 2.f * acc[kt][tn][rr];
          rmin[tn] = fminf(rmin[tn], d2);
        }
      }
    }
  }

  // min across the 4 lane-groups (they hold disjoint k rows, same t cols)
  #pragma unroll
  for (int tn = 0; tn < 4; ++tn) {
    rmin[tn] = fminf(rmin[tn], __shfl_xor(rmin[tn], 16));
    rmin[tn] = fminf(rmin[tn], __shfl_xor(rmin[tn], 32));
  }
  if (g == 0) {
    #pragma unroll
    for (int tn = 0; tn < 4; ++tn) wmin[wv][tn * 16 + r16] = rmin[tn];
  }
  __syncthreads();

  if (tid < 64) {
    float v = fminf(fminf(wmin[0][tid], wmin[1][tid]),
                    fminf(wmin[2][tid], wmin[3][tid])) + hsum[tid];
    #pragma unroll
    for (int off = 32; off > 0; off >>= 1) v += __shfl_down(v, off);
    if (tid == 0) atomicAdd(&accums[2], v);
  }
}

// ---------------------------------------------------------------------------
// Kernel 4: combine scalars.
// loss = recsum/262144 + 0.25*2*d2sum/8388608 - 0.1*dhatsum/32768
// ---------------------------------------------------------------------------
__global__ void edm_fin(const float* __restrict__ accums, float* __restrict__ out) {
  out[0] = accums[0] * (1.f / 262144.f)
         + accums[2] * (1.f / 16777216.f)
         - 0.1f * accums[1] * (1.f / 32768.f);
}

extern "C" void kernel_launch(void* const* d_in, const int* in_sizes, int n_in,
                              void* d_out, int out_size, void* d_ws, size_t ws_size,
                              hipStream_t stream) {
  const float* Xh = (const float*)d_in[0];   // [64,8,512]
  const float* X  = (const float*)d_in[1];   // [64,8,512]
  const float* H  = (const float*)d_in[2];   // [64,256,512]
  const float* M  = (const float*)d_in[3];   // [256,512]
  const float* Dh = (const float*)d_in[4];   // [64,512]
  float* out = (float*)d_out;

  unsigned short* Mt = (unsigned short*)d_ws;                     // 512*256*2 = 256 KiB
  float* mnorm  = (float*)((char*)d_ws + (size_t)KK * DD * 2);    // 512 floats
  float* accums = mnorm + KK;                                     // [rec, dhat, d2sum]

  edm_prep_m<<<KK, 256, 0, stream>>>(M, Mt, mnorm, accums);
  edm_rec<<<256, 256, 0, stream>>>((const float4*)Xh, (const float4*)X,
                                   (const float4*)Dh, accums);
  edm_main<<<NB * (TT / 64), 256, 0, stream>>>(H, Mt, mnorm, accums);
  edm_fin<<<1, 1, 0, stream>>>(accums, out);
}

// Round 2
// 26.494 us; speedup vs baseline: 1.8981x; 1.8981x over previous
//
#include <hip/hip_runtime.h>

// Problem constants
#define NB   64    // B
#define DD   256   // D
#define TT   512   // T
#define KK   512   // K

typedef short bf8 __attribute__((ext_vector_type(8)));   // 8 x bf16 bits (4 VGPR)
typedef float f4  __attribute__((ext_vector_type(4)));   // MFMA acc

__device__ inline unsigned short f2bf(float x) {
  unsigned u = __float_as_uint(x);
  u += 0x7FFFu + ((u >> 16) & 1u);   // round-to-nearest-even
  return (unsigned short)(u >> 16);
}

// D = A*B + D   (A rows = codewords k, B cols = t, reduction = d)
#define MFMA(accv, va, vb) \
  asm("v_mfma_f32_16x16x32_bf16 %0, %1, %2, %0" : "+v"(accv) : "v"(va), "v"(vb))

#define ACCROW(acc, kt) \
    "+v"(acc[kt][0]), "+v"(acc[kt][1]), "+v"(acc[kt][2]), "+v"(acc[kt][3]), \
    "+v"(acc[kt][4]), "+v"(acc[kt][5]), "+v"(acc[kt][6]), "+v"(acc[kt][7])
#define ACCLIST8(acc) ACCROW(acc,0), ACCROW(acc,1), ACCROW(acc,2), ACCROW(acc,3)

// ---------------------------------------------------------------------------
// Kernel 1 (fused):
//   blocks 0..7  : tiled coalesced transpose M [D][K] -> Mt [K][D] bf16 + mnorm
//   blocks 8..71 : rec partial sums (Xhat-X)^2 and Dhat partial sums
// ---------------------------------------------------------------------------
__global__ __launch_bounds__(256) void edm_prep(
    const float* __restrict__ M, const float4* __restrict__ Xh,
    const float4* __restrict__ X, const float4* __restrict__ Dh,
    unsigned short* __restrict__ Mt, float* __restrict__ mnorm,
    float* __restrict__ recp, float* __restrict__ dhp) {
  __shared__ __align__(16) float tile[DD][68];   // 68 KiB, row stride 272 B (16B-aligned)
  __shared__ float pn[4][64];
  __shared__ float ps[8];

  const int bid  = blockIdx.x;
  const int tid  = threadIdx.x;
  const int lane = tid & 63;
  const int q    = tid >> 6;

  if (bid < 8) {
    // ---- transpose block: k-range [bid*64, +64), all 256 d ----
    #pragma unroll
    for (int it = 0; it < 16; ++it) {            // wave q loads rows q*64..+64
      const int d  = q * 64 + it * 4 + (lane >> 4);
      const int kc = (lane & 15) << 2;
      const float4 v = *(const float4*)(M + (size_t)d * KK + bid * 64 + kc);
      *(float4*)&tile[d][kc] = v;
    }
    __syncthreads();
    // thread (q, lane): k-col = lane, d-range q*64..+64
    const int k = bid * 64 + lane;
    float s = 0.f;
    #pragma unroll
    for (int c = 0; c < 8; ++c) {                // 8 x 8 d
      unsigned pk[4];
      #pragma unroll
      for (int e = 0; e < 4; ++e) {
        const float x0 = tile[q * 64 + c * 8 + 2 * e + 0][lane];
        const float x1 = tile[q * 64 + c * 8 + 2 * e + 1][lane];
        s += x0 * x0 + x1 * x1;
        pk[e] = (unsigned)f2bf(x0) | ((unsigned)f2bf(x1) << 16);
      }
      *(uint4*)(Mt + (size_t)k * DD + q * 64 + c * 8) =
          make_uint4(pk[0], pk[1], pk[2], pk[3]);
    }
    pn[q][lane] = s;
    __syncthreads();
    if (q == 0) mnorm[k] = pn[0][lane] + pn[1][lane] + pn[2][lane] + pn[3][lane];
  } else {
    // ---- rec block ----
    const int r = bid - 8;
    float s = 0.f, sd = 0.f;
    #pragma unroll
    for (int i = 0; i < 4; ++i) {
      const int idx = r * 1024 + i * 256 + tid;
      const float4 a = Xh[idx];
      const float4 c = X[idx];
      const float e0 = a.x - c.x, e1 = a.y - c.y, e2 = a.z - c.z, e3 = a.w - c.w;
      s += e0 * e0 + e1 * e1 + e2 * e2 + e3 * e3;
    }
    if (tid < 128) {
      const float4 dd = Dh[r * 128 + tid];
      sd = dd.x + dd.y + dd.z + dd.w;
    }
    #pragma unroll
    for (int off = 32; off > 0; off >>= 1) {
      s  += __shfl_down(s, off);
      sd += __shfl_down(sd, off);
    }
    if (lane == 0) { ps[q] = s; ps[4 + q] = sd; }
    __syncthreads();
    if (tid == 0) {
      recp[r] = ps[0] + ps[1] + ps[2] + ps[3];
      dhp[r]  = ps[4] + ps[5] + ps[6] + ps[7];
    }
  }
}

// ---------------------------------------------------------------------------
// Kernel 2: main. 512 threads (8 waves), one block per (b, t-tile of 128).
//   d2min[t] = min_k (||m_k||^2 - 2 h_t . m_k) + ||h_t||^2 ; block writes
//   d2part[bid] = sum over its 128 t.
// Wave wv owns k in [wv*64, wv*64+64), all 128 t (acc[4][8]).
// ---------------------------------------------------------------------------
__global__ __launch_bounds__(512, 2) void edm_main(
    const float* __restrict__ H, const unsigned short* __restrict__ Mt,
    const float* __restrict__ mnorm, float* __restrict__ d2part) {
  __shared__ __align__(16) float scratch[64][132];          // fp32 transpose staging
  __shared__ __align__(16) unsigned short Hbf[128 * 256];   // [t][d] bf16, XOR-swizzled
  __shared__ float hsum[128];
  __shared__ float wmin[8][128];
  __shared__ float bsum[2];

  const int tid = threadIdx.x;
  const int b   = blockIdx.x >> 2;
  const int t0  = (blockIdx.x & 3) << 7;
  const float* Hb = H + (size_t)b * DD * TT + t0;

  if (tid < 128) hsum[tid] = 0.f;

  const int tcol = tid & 127;
  const int q    = tid >> 7;
  float hacc = 0.f;

  for (int ch = 0; ch < 4; ++ch) {              // 4 chunks of 64 d-rows x 128 t
    #pragma unroll
    for (int ii = 0; ii < 4; ++ii) {            // coalesced global -> fp32 scratch
      const int f  = ii * 512 + tid;
      const int dl = f >> 5;
      const int t4 = (f & 31) << 2;
      const float4 v = *(const float4*)(Hb + (size_t)(ch * 64 + dl) * TT + t4);
      *(float4*)&scratch[dl][t4] = v;
    }
    __syncthreads();
    unsigned wpk[8];
    #pragma unroll
    for (int jj = 0; jj < 8; ++jj) {            // column read, convert, pack
      const float x0 = scratch[q * 16 + 2 * jj + 0][tcol];
      const float x1 = scratch[q * 16 + 2 * jj + 1][tcol];
      hacc += x0 * x0 + x1 * x1;
      wpk[jj] = (unsigned)f2bf(x0) | ((unsigned)f2bf(x1) << 16);
    }
    char* rowp = (char*)Hbf + tcol * 512;
    const int dbase2 = (ch * 64 + q * 16) * 2;
    const int swz = (tcol & 7) << 4;
    *(uint4*)(rowp + ((dbase2 +  0) ^ swz)) = make_uint4(wpk[0], wpk[1], wpk[2], wpk[3]);
    *(uint4*)(rowp + ((dbase2 + 16) ^ swz)) = make_uint4(wpk[4], wpk[5], wpk[6], wpk[7]);
    __syncthreads();
  }
  atomicAdd(&hsum[tcol], hacc);   // LDS atomic; consumed after post-wmin barrier

  // ---- MFMA phase ----
  const int l   = tid & 63;
  const int wv  = tid >> 6;
  const int kb  = wv << 6;
  const int r16 = l & 15;
  const int g   = l >> 4;

  float rmin[8] = {3.0e38f, 3.0e38f, 3.0e38f, 3.0e38f,
                   3.0e38f, 3.0e38f, 3.0e38f, 3.0e38f};
  f4 acc[4][8];
  #pragma unroll
  for (int kt = 0; kt < 4; ++kt)
    #pragma unroll
    for (int tn = 0; tn < 8; ++tn)
      acc[kt][tn] = (f4){0.f, 0.f, 0.f, 0.f};
  asm volatile("s_nop 1" : ACCLIST8(acc));      // VALU-write -> MFMA-read-C guard

  #pragma unroll
  for (int ds = 0; ds < 8; ++ds) {              // 8 x K=32 over d
    bf8 afr[4];
    #pragma unroll
    for (int kt = 0; kt < 4; ++kt)
      afr[kt] = *(const bf8*)(Mt + (size_t)(kb + kt * 16 + r16) * DD + ds * 32 + g * 8);
    #pragma unroll
    for (int tn = 0; tn < 8; ++tn) {
      const int t = tn * 16 + r16;
      const bf8 bfr = *(const bf8*)((const char*)Hbf + t * 512 +
                                    ((ds * 64 + g * 16) ^ ((t & 7) << 4)));
      MFMA(acc[0][tn], afr[0], bfr);
      MFMA(acc[1][tn], afr[1], bfr);
      MFMA(acc[2][tn], afr[2], bfr);
      MFMA(acc[3][tn], afr[3], bfr);
    }
  }
  asm volatile("s_nop 7\n\ts_nop 7" : ACCLIST8(acc));  // MFMA-write -> VALU-read guard

  // fold: k = kb + kt*16 + 4*g + rr (C/D row map: col=lane&15, row=4*(l>>4)+reg)
  #pragma unroll
  for (int kt = 0; kt < 4; ++kt) {
    const f4 mn = *(const f4*)(mnorm + kb + kt * 16 + g * 4);
    #pragma unroll
    for (int tn = 0; tn < 8; ++tn) {
      #pragma unroll
      for (int rr = 0; rr < 4; ++rr) {
        const float d2 = mn[rr] - 2.f * acc[kt][tn][rr];
        rmin[tn] = fminf(rmin[tn], d2);
      }
    }
  }

  // min across the 4 lane-groups (disjoint k rows, same t cols)
  #pragma unroll
  for (int tn = 0; tn < 8; ++tn) {
    rmin[tn] = fminf(rmin[tn], __shfl_xor(rmin[tn], 16));
    rmin[tn] = fminf(rmin[tn], __shfl_xor(rmin[tn], 32));
  }
  if (g == 0) {
    #pragma unroll
    for (int tn = 0; tn < 8; ++tn) wmin[wv][tn * 16 + r16] = rmin[tn];
  }
  __syncthreads();

  if (tid < 128) {
    float m = wmin[0][tid];
    #pragma unroll
    for (int w = 1; w < 8; ++w) m = fminf(m, wmin[w][tid]);
    float v = m + hsum[tid];
    #pragma unroll
    for (int off = 32; off > 0; off >>= 1) v += __shfl_down(v, off);
    if ((tid & 63) == 0) bsum[tid >> 6] = v;
  }
  __syncthreads();
  if (tid == 0) d2part[blockIdx.x] = bsum[0] + bsum[1];
}

// ---------------------------------------------------------------------------
// Kernel 3: deterministic final reduce + combine.
// loss = recsum/262144 + 2*0.25*d2sum/8388608 - 0.1*dhatsum/32768
// ---------------------------------------------------------------------------
__global__ __launch_bounds__(256) void edm_fin(
    const float* __restrict__ recp, const float* __restrict__ dhp,
    const float* __restrict__ d2p, float* __restrict__ out) {
  const int tid = threadIdx.x;
  float a  = d2p[tid];                               // 256 entries
  float r  = (tid < 64) ? recp[tid] : 0.f;
  float dh = (tid < 64) ? dhp[tid]  : 0.f;
  #pragma unroll
  for (int off = 32; off > 0; off >>= 1) {
    a  += __shfl_down(a, off);
    r  += __shfl_down(r, off);
    dh += __shfl_down(dh, off);
  }
  __shared__ float pa[4], pr[4], pd[4];
  const int w = tid >> 6;
  if ((tid & 63) == 0) { pa[w] = a; pr[w] = r; pd[w] = dh; }
  __syncthreads();
  if (tid == 0) {
    const float d2sum  = pa[0] + pa[1] + pa[2] + pa[3];
    const float recsum = pr[0] + pr[1] + pr[2] + pr[3];
    const float dhsum  = pd[0] + pd[1] + pd[2] + pd[3];
    out[0] = recsum * (1.f / 262144.f)
           + d2sum  * (1.f / 16777216.f)
           - 0.1f * dhsum * (1.f / 32768.f);
  }
}

extern "C" void kernel_launch(void* const* d_in, const int* in_sizes, int n_in,
                              void* d_out, int out_size, void* d_ws, size_t ws_size,
                              hipStream_t stream) {
  const float* Xh = (const float*)d_in[0];   // [64,8,512]
  const float* X  = (const float*)d_in[1];   // [64,8,512]
  const float* H  = (const float*)d_in[2];   // [64,256,512]
  const float* M  = (const float*)d_in[3];   // [256,512]
  const float* Dh = (const float*)d_in[4];   // [64,512]
  float* out = (float*)d_out;

  unsigned short* Mt = (unsigned short*)d_ws;                      // 256 KiB
  float* mnorm = (float*)((char*)d_ws + (size_t)KK * DD * 2);      // 512 f
  float* recp  = mnorm + KK;                                       // 64 f
  float* dhp   = recp + 64;                                        // 64 f
  float* d2p   = dhp + 64;                                         // 256 f

  edm_prep<<<72, 256, 0, stream>>>(M, (const float4*)Xh, (const float4*)X,
                                   (const float4*)Dh, Mt, mnorm, recp, dhp);
  edm_main<<<NB * (TT / 128), 512, 0, stream>>>(H, Mt, mnorm, d2p);
  edm_fin<<<1, 256, 0, stream>>>(recp, dhp, d2p, out);
}